// Round 3
// baseline (394.522 us; speedup 1.0000x reference)
//
#include <hip/hip_runtime.h>

#define ED 128   // embedding dim (== RD); 32 float4 per row

typedef float vfloat4 __attribute__((ext_vector_type(4)));  // native vec for nt-store

// Two samples per wave: lanes 0-31 handle sample 2*wid, lanes 32-63 handle
// sample 2*wid+1. Each lane loads one float4 (16 B) -> each 512 B embedding
// row is one contiguous 32-lane segment. Butterfly reduction uses xor masks
// 16..1, which never cross the 32-lane half boundary, so both samples'
// reductions happen in the same 5 steps.
//
// Math (collapsed from the reference; eye is the 128x128 identity):
//   h_out = rp_hat * dot(hp_hat, hv_hat) + hv_hat
//   rv_out = rv_hat
//   t_out = rp_hat * dot(tp_hat, tv_hat) + tv_hat
// where x_hat = x * sc_x, sc_x = (||x|| > 1) ? 1/(||x||+1e-7) : 1
// and dot(x_hat, y_hat) = sc_x * sc_y * dot(x, y).

__device__ __forceinline__ float dot4(vfloat4 a, vfloat4 b) {
    return a.x * b.x + a.y * b.y + a.z * b.z + a.w * b.w;
}

__global__ __launch_bounds__(256) void transd_kernel(
    const float* __restrict__ ent,   // [ENT, 128]
    const float* __restrict__ entp,  // [ENT, 128]
    const float* __restrict__ rel,   // [REL, 128]
    const float* __restrict__ relp,  // [REL, 128]
    const int* __restrict__ h,
    const int* __restrict__ r,
    const int* __restrict__ t,
    float* __restrict__ out,         // [3, B, 128] concat: h_out, rv, t_out
    int B)
{
    const int wid    = (blockIdx.x * blockDim.x + threadIdx.x) >> 6;
    const int lane   = threadIdx.x & 63;
    const int half   = lane >> 5;         // which sample within the wave
    const int sub    = lane & 31;         // lane within the 32-lane half
    const int sample = wid * 2 + half;
    if (sample >= B) return;

    const int hi = h[sample];
    const int ri = r[sample];
    const int ti = t[sample];

    const vfloat4 hp = ((const vfloat4*)(entp + (size_t)hi * ED))[sub];
    const vfloat4 hv = ((const vfloat4*)(ent  + (size_t)hi * ED))[sub];
    const vfloat4 rp = ((const vfloat4*)(relp + (size_t)ri * ED))[sub];
    const vfloat4 rv = ((const vfloat4*)(rel  + (size_t)ri * ED))[sub];
    const vfloat4 tp = ((const vfloat4*)(entp + (size_t)ti * ED))[sub];
    const vfloat4 tv = ((const vfloat4*)(ent  + (size_t)ti * ED))[sub];

    // per-lane partials: 6 squared norms + 2 raw dots
    float s_hp = dot4(hp, hp);
    float s_hv = dot4(hv, hv);
    float s_rp = dot4(rp, rp);
    float s_rv = dot4(rv, rv);
    float s_tp = dot4(tp, tp);
    float s_tv = dot4(tv, tv);
    float d_h  = dot4(hp, hv);
    float d_t  = dot4(tp, tv);

    // 32-lane butterfly (xor masks <32 stay within each half-wave)
    #pragma unroll
    for (int off = 16; off >= 1; off >>= 1) {
        s_hp += __shfl_xor(s_hp, off);
        s_hv += __shfl_xor(s_hv, off);
        s_rp += __shfl_xor(s_rp, off);
        s_rv += __shfl_xor(s_rv, off);
        s_tp += __shfl_xor(s_tp, off);
        s_tv += __shfl_xor(s_tv, off);
        d_h  += __shfl_xor(d_h,  off);
        d_t  += __shfl_xor(d_t,  off);
    }

    auto renorm_scale = [](float s2) -> float {
        float n = sqrtf(s2);
        return (n > 1.0f) ? (1.0f / (n + 1e-7f)) : 1.0f;
    };

    const float sc_hp = renorm_scale(s_hp);
    const float sc_hv = renorm_scale(s_hv);
    const float sc_rp = renorm_scale(s_rp);
    const float sc_rv = renorm_scale(s_rv);
    const float sc_tp = renorm_scale(s_tp);
    const float sc_tv = renorm_scale(s_tv);

    const float gh = sc_rp * (d_h * sc_hp * sc_hv);  // rp coefficient for h_out
    const float gt = sc_rp * (d_t * sc_tp * sc_tv);  // rp coefficient for t_out

    vfloat4 h_out, rv_out, t_out;
    h_out  = rp * gh + hv * sc_hv;
    rv_out = rv * sc_rv;
    t_out  = rp * gt + tv * sc_tv;

    const size_t row  = (size_t)sample * 32 + sub;   // in vfloat4 units
    const size_t sect = (size_t)B * 32;              // one output section
    vfloat4* o = (vfloat4*)out;
    __builtin_nontemporal_store(h_out,  o + row);
    __builtin_nontemporal_store(rv_out, o + sect + row);
    __builtin_nontemporal_store(t_out,  o + 2 * sect + row);
}

extern "C" void kernel_launch(void* const* d_in, const int* in_sizes, int n_in,
                              void* d_out, int out_size, void* d_ws, size_t ws_size,
                              hipStream_t stream) {
    const float* ent  = (const float*)d_in[0];
    const float* entp = (const float*)d_in[1];
    const float* rel  = (const float*)d_in[2];
    const float* relp = (const float*)d_in[3];
    const int*   h    = (const int*)d_in[4];
    const int*   r    = (const int*)d_in[5];
    const int*   t    = (const int*)d_in[6];
    float* out = (float*)d_out;

    const int B = in_sizes[4];           // 8192
    const int samples_per_block = 8;     // 256 threads = 4 waves, 2 samples/wave
    const int grid = (B + samples_per_block - 1) / samples_per_block;
    transd_kernel<<<grid, 256, 0, stream>>>(ent, entp, rel, relp, h, r, t, out, B);
}